// Round 2
// baseline (537.408 us; speedup 1.0000x reference)
//
#include <hip/hip_runtime.h>
#include <math.h>

// ---------------- problem constants ----------------
#define BB 262144
#define NST 20
#define RHc 0.006f            // R*H
#define BHc 0.01f             // B_DRIFT*H
#define SIGc 0.2f
#define CURTc 0.005f
#define DISCf 0.8869204367171575f   // exp(-0.12)

// ---------------- launch geometry ----------------
#define P 4                   // paths per thread (amortizes LDS weight reads)
#define THB 256
#define NBLK 256              // sim blocks AND post blocks
#define CH 65536              // chunk stride = BB / P

// ---------------- workspace layout (4-byte units) ----------------
#define SIMP_OFF  BB                       // float[NBLK*5]
#define TAILP_OFF (SIMP_OFF + NBLK * 5)    // float[NBLK*4]
#define ICTRL     (TAILP_OFF + NBLK * 4)   // int region begins
// ctrl (int) layout
#define H1_OFF 0                            // 2048
#define H2_OFF 2048                         // 4*2048
#define H3_OFF (H2_OFF + 4 * 2048)          // 4*1024
#define HTOT   (H3_OFF + 4 * 1024)          // 14336
#define CNT_OFF HTOT                        // sim last-block counter
#define GB_OFF  (HTOT + 1)                  // grid-barrier counter
#define ST_OFF  (HTOT + 8)                  // ints: P1[4] R1[4] G2[4] P2[4] R2[4] G3[4]
#define SF_OFF  (ST_OFF + 24)               // floats: vals[4], p5, p95
#define ZERO_N  8                           // ints to zero at CNT_OFF

// ---------------- helpers ----------------
__device__ __forceinline__ unsigned fkey(float f) {
    unsigned u = __float_as_uint(f);
    return (u & 0x80000000u) ? ~u : (u | 0x80000000u);
}
__device__ __forceinline__ float funkey(unsigned k) {
    return __uint_as_float((k & 0x80000000u) ? (k ^ 0x80000000u) : ~k);
}
__device__ __forceinline__ float wred(float v) {
#pragma unroll
    for (int o = 32; o > 0; o >>= 1) v += __shfl_down(v, o);
    return v;
}
// device-scope grid barrier (all NBLK blocks co-resident by construction)
__device__ __forceinline__ void gbar(int* cnt, int target) {
    __syncthreads();
    __threadfence();   // release: make prior stores visible device-wide
    if (threadIdx.x == 0) {
        __hip_atomic_fetch_add(cnt, 1, __ATOMIC_ACQ_REL, __HIP_MEMORY_SCOPE_AGENT);
        while (__hip_atomic_load(cnt, __ATOMIC_ACQUIRE, __HIP_MEMORY_SCOPE_AGENT) < target)
            __builtin_amdgcn_s_sleep(2);
    }
    __syncthreads();
    __threadfence();   // acquire: invalidate caches before reading others' data
}

// ---------------- zero control region ----------------
__global__ void zero_kernel(int* __restrict__ ctrl) {
    int i = threadIdx.x;
    if (i < ZERO_N) ctrl[CNT_OFF + i] = 0;
}

// 20-wide FMA accumulate / dot macros (all indices compile-time after unroll)
#define ACC20(P_) do { \
  h2[P_][0]=fmaf(hv,wa.x,h2[P_][0]);  h2[P_][1]=fmaf(hv,wa.y,h2[P_][1]); \
  h2[P_][2]=fmaf(hv,wa.z,h2[P_][2]);  h2[P_][3]=fmaf(hv,wa.w,h2[P_][3]); \
  h2[P_][4]=fmaf(hv,wb2.x,h2[P_][4]); h2[P_][5]=fmaf(hv,wb2.y,h2[P_][5]); \
  h2[P_][6]=fmaf(hv,wb2.z,h2[P_][6]); h2[P_][7]=fmaf(hv,wb2.w,h2[P_][7]); \
  h2[P_][8]=fmaf(hv,wc2.x,h2[P_][8]); h2[P_][9]=fmaf(hv,wc2.y,h2[P_][9]); \
  h2[P_][10]=fmaf(hv,wc2.z,h2[P_][10]); h2[P_][11]=fmaf(hv,wc2.w,h2[P_][11]); \
  h2[P_][12]=fmaf(hv,wd2.x,h2[P_][12]); h2[P_][13]=fmaf(hv,wd2.y,h2[P_][13]); \
  h2[P_][14]=fmaf(hv,wd2.z,h2[P_][14]); h2[P_][15]=fmaf(hv,wd2.w,h2[P_][15]); \
  h2[P_][16]=fmaf(hv,we2.x,h2[P_][16]); h2[P_][17]=fmaf(hv,we2.y,h2[P_][17]); \
  h2[P_][18]=fmaf(hv,we2.z,h2[P_][18]); h2[P_][19]=fmaf(hv,we2.w,h2[P_][19]); \
} while (0)

#define DOT20(P_) do { \
  a=fmaf(h2[P_][0],wa.x,a);  a=fmaf(h2[P_][1],wa.y,a);  a=fmaf(h2[P_][2],wa.z,a);  a=fmaf(h2[P_][3],wa.w,a); \
  a=fmaf(h2[P_][4],wb2.x,a); a=fmaf(h2[P_][5],wb2.y,a); a=fmaf(h2[P_][6],wb2.z,a); a=fmaf(h2[P_][7],wb2.w,a); \
  a=fmaf(h2[P_][8],wc2.x,a); a=fmaf(h2[P_][9],wc2.y,a); a=fmaf(h2[P_][10],wc2.z,a); a=fmaf(h2[P_][11],wc2.w,a); \
  a=fmaf(h2[P_][12],wd2.x,a); a=fmaf(h2[P_][13],wd2.y,a); a=fmaf(h2[P_][14],wd2.z,a); a=fmaf(h2[P_][15],wd2.w,a); \
  a=fmaf(h2[P_][16],we2.x,a); a=fmaf(h2[P_][17],we2.y,a); a=fmaf(h2[P_][18],we2.z,a); a=fmaf(h2[P_][19],we2.w,a); \
} while (0)

// ---------------- main simulation: P=4 paths per thread ----------------
__global__ __launch_bounds__(THB, 1) void sim_kernel(
    const float* __restrict__ x_in, const float* __restrict__ dW,
    const float* __restrict__ Wo, const float* __restrict__ bo,
    const float* __restrict__ Wk, const float* __restrict__ bk,
    const float* __restrict__ Wu0, const float* __restrict__ bu0,
    const float* __restrict__ W1, const float* __restrict__ b1,
    const float* __restrict__ W2, const float* __restrict__ b2,
    const float* __restrict__ W3, const float* __restrict__ b3,
    float* __restrict__ ws, int* __restrict__ ctrl, float* __restrict__ out)
{
    // LDS layout per step s (stride 568 floats):
    // [0,20) W1row | [20,40) b1 | [40,440) W2 row-major | [440,460) b2 |
    // [460,560) W3T (5 rows x 20) | [560,565) b3
    __shared__ float L[10844];
    __shared__ float red[4][5];
    __shared__ int lastF;
    const int tid = threadIdx.x;

    for (int t = tid; t < 19 * 20; t += THB) {
        int s = t / 20, j = t % 20;
        L[s * 568 + j]       = W1[t];
        L[s * 568 + 20 + j]  = b1[t];
        L[s * 568 + 440 + j] = b2[t];
    }
    for (int t = tid; t < 19 * 400; t += THB) {
        int s = t / 400, r = t % 400;
        L[s * 568 + 40 + r] = W2[t];
    }
    for (int t = tid; t < 19 * 100; t += THB) {
        int s = t / 100, r = t % 100, i = r / 5, k = r % 5;
        L[s * 568 + 460 + k * 20 + i] = W3[t];
    }
    for (int t = tid; t < 19 * 5; t += THB) {
        int s = t / 5, k = t % 5;
        L[s * 568 + 560 + k] = b3[t];
    }
    if (tid < 11) { L[10792 + tid] = Wo[tid]; L[10803 + tid] = bo[tid]; }
    if (tid < 10) { L[10814 + tid] = Wk[tid]; L[10824 + tid] = bk[tid]; }
    if (tid < 5)  { L[10834 + tid] = Wu0[tid]; L[10839 + tid] = bu0[tid]; }
    __syncthreads();

    const int b0 = blockIdx.x * THB + tid;

    float x[P], K0[P], smv = 0.f;
    float alpha[P][5], S[P][5], SQ[P][5], dN[P][5], Nm1[P][5], dwb[P][5];

#pragma unroll
    for (int p = 0; p < P; p++) {
        int b = b0 + p * CH;
        float xx = x_in[b];
        x[p] = xx;
        float z[11], zm = -1e30f;
#pragma unroll
        for (int j = 0; j < 11; j++) {
            z[j] = fmaf(xx, L[10792 + j], L[10803 + j]);
            zm = fmaxf(zm, z[j]);
        }
        float se = 0.f;
#pragma unroll
        for (int j = 0; j < 11; j++) se += __expf(z[j] - zm);
        smv += __expf(z[10] - zm) / se;
        K0[p] = 1.f + 0.25f * tanhf(fmaf(xx, L[10814], L[10824]));
#pragma unroll
        for (int d = 0; d < 5; d++) {
            alpha[p][d] = fmaf(xx, L[10834 + d], L[10839 + d]);
            S[p][d] = 1.f; SQ[p][d] = 1.f; dN[p][d] = 0.f;
            Nm1[p][d] = alpha[p][d];
        }
        const float* pw = dW + (size_t)b * 5;
#pragma unroll
        for (int d = 0; d < 5; d++) dwb[p][d] = pw[d];
    }

#pragma unroll 1
    for (int n = 1; n <= NST; n++) {
        float dwc[P][5];
#pragma unroll
        for (int p = 0; p < P; p++)
#pragma unroll
            for (int d = 0; d < 5; d++) dwc[p][d] = dwb[p][d];
        if (n < NST) {  // prefetch next step's noise (hides under MLP)
#pragma unroll
            for (int p = 0; p < P; p++) {
                const float* pw = dW + ((size_t)n * BB + b0 + p * CH) * 5;
#pragma unroll
                for (int d = 0; d < 5; d++) dwb[p][d] = pw[d];
            }
        }
        // wealth / price Euler step
#pragma unroll
        for (int p = 0; p < P; p++) {
            float usum = 0.f, du = 0.f;
#pragma unroll
            for (int d = 0; d < 5; d++) {
                float u = alpha[p][d];
                float Np = u * __builtin_amdgcn_rcpf(S[p][d]);
                dN[p][d] += fabsf(Np - Nm1[p][d]);
                Nm1[p][d] = Np;
                usum += u;
                du = fmaf(u, fmaf(SIGc, dwc[p][d], BHc), du);
            }
            x[p] = fmaf(x[p] - usum, RHc, x[p]) + du;
#pragma unroll
            for (int d = 0; d < 5; d++) {
                float g = SIGc * dwc[p][d];
                S[p][d]  *= (1.f + BHc + g);
                SQ[p][d] *= (1.f + RHc + g);
            }
        }
        if (n < NST) {
            const float* Ls = L + (n - 1) * 568;
            float h2[P][20];
#pragma unroll
            for (int j4 = 0; j4 < 5; j4++) {
                float4 c = *(const float4*)(Ls + 440 + j4 * 4);
#pragma unroll
                for (int p = 0; p < P; p++) {
                    h2[p][j4 * 4 + 0] = c.x; h2[p][j4 * 4 + 1] = c.y;
                    h2[p][j4 * 4 + 2] = c.z; h2[p][j4 * 4 + 3] = c.w;
                }
            }
#pragma unroll 1
            for (int i4 = 0; i4 < 5; i4++) {
                float4 w1c = *(const float4*)(Ls + i4 * 4);
                float4 c1c = *(const float4*)(Ls + 20 + i4 * 4);
                const float* wr0 = Ls + 40 + i4 * 80;
#pragma unroll
                for (int ii = 0; ii < 4; ii++) {
                    const float* wr = wr0 + ii * 20;
                    float4 wa  = *(const float4*)(wr + 0);
                    float4 wb2 = *(const float4*)(wr + 4);
                    float4 wc2 = *(const float4*)(wr + 8);
                    float4 wd2 = *(const float4*)(wr + 12);
                    float4 we2 = *(const float4*)(wr + 16);
                    float wv = (ii == 0) ? w1c.x : (ii == 1) ? w1c.y : (ii == 2) ? w1c.z : w1c.w;
                    float cv = (ii == 0) ? c1c.x : (ii == 1) ? c1c.y : (ii == 2) ? c1c.z : c1c.w;
#pragma unroll
                    for (int p = 0; p < P; p++) {
                        float hv = fmaxf(fmaf(x[p], wv, cv), 0.f);
                        ACC20(p);
                    }
                }
            }
#pragma unroll
            for (int p = 0; p < P; p++)
#pragma unroll
                for (int j = 0; j < 20; j++) h2[p][j] = fmaxf(h2[p][j], 0.f);
#pragma unroll
            for (int k = 0; k < 5; k++) {
                const float* wr = Ls + 460 + k * 20;
                float4 wa  = *(const float4*)(wr + 0);
                float4 wb2 = *(const float4*)(wr + 4);
                float4 wc2 = *(const float4*)(wr + 8);
                float4 wd2 = *(const float4*)(wr + 12);
                float4 we2 = *(const float4*)(wr + 16);
                float bb = Ls[560 + k];
#pragma unroll
                for (int p = 0; p < P; p++) {
                    float a = bb;
                    DOT20(p);
                    alpha[p][k] = a;
                }
            }
        }
    }

    float v0 = 0.f, v1 = 0.f, v2 = 0.f, v3 = 0.f, v4 = smv;
#pragma unroll
    for (int p = 0; p < P; p++) {
        float dNs = dN[p][0] + dN[p][1] + dN[p][2] + dN[p][3] + dN[p][4];
        float xx = fmaf(-CURTc, dNs, x[p]);
        ws[b0 + p * CH] = xx;
        v0 += xx; v1 += xx * xx;
        v2 += fmaxf(S[p][0]  - K0[p], 0.f);
        v3 += fmaxf(SQ[p][0] - K0[p], 0.f);
    }

    v0 = wred(v0); v1 = wred(v1); v2 = wred(v2); v3 = wred(v3); v4 = wred(v4);
    int wid = tid >> 6, lane = tid & 63;
    if (lane == 0) { red[wid][0] = v0; red[wid][1] = v1; red[wid][2] = v2; red[wid][3] = v3; red[wid][4] = v4; }
    __syncthreads();
    if (tid == 0) {
        float s0 = 0, s1 = 0, s2 = 0, s3 = 0, s4 = 0;
#pragma unroll
        for (int w = 0; w < 4; w++) { s0 += red[w][0]; s1 += red[w][1]; s2 += red[w][2]; s3 += red[w][3]; s4 += red[w][4]; }
        float* part = ws + SIMP_OFF + blockIdx.x * 5;
        part[0] = s0; part[1] = s1; part[2] = s2; part[3] = s3; part[4] = s4;
    }
    __threadfence();
    if (tid == 0) lastF = (atomicAdd(&ctrl[CNT_OFF], 1) == (int)gridDim.x - 1);
    __syncthreads();
    if (!lastF) return;
    __threadfence();

    const float* part = ws + SIMP_OFF;
    float a0 = part[tid * 5 + 0], a1 = part[tid * 5 + 1], a2 = part[tid * 5 + 2],
          a3 = part[tid * 5 + 3], a4 = part[tid * 5 + 4];
    a0 = wred(a0); a1 = wred(a1); a2 = wred(a2); a3 = wred(a3); a4 = wred(a4);
    if (lane == 0) { red[wid][0] = a0; red[wid][1] = a1; red[wid][2] = a2; red[wid][3] = a3; red[wid][4] = a4; }
    __syncthreads();
    if (tid == 0) {
        float Sx = 0, Sx2 = 0, SP = 0, SQs = 0, Ssm = 0;
#pragma unroll
        for (int w = 0; w < 4; w++) { Sx += red[w][0]; Sx2 += red[w][1]; SP += red[w][2]; SQs += red[w][3]; Ssm += red[w][4]; }
        float invB = 1.f / (float)BB;
        float meanx = Sx * invB;
        out[0] = -meanx;
        out[1] = Sx2 * invB - meanx * meanx;
        out[4] = (SP * invB) / (DISCf * (SQs * invB) + 1e-8f);
        out[5] = 1.f + 0.25f * tanhf(fmaf(x_in[0], Wk[1], bk[1]));
        out[6] = Ssm * invB;
    }
}

// ---------------- fused select + tail kernel ----------------
__device__ __forceinline__ void aggAdd(int* lh, int code) {
    bool act = (code >= 0);
    unsigned long long mask = __ballot(act);
    while (mask) {
        int leader = __ffsll((unsigned long long)mask) - 1;
        int lc = __shfl(code, leader);
        unsigned long long mm = __ballot(act && code == lc);
        if ((threadIdx.x & 63) == leader) atomicAdd(&lh[lc], (int)__popcll(mm));
        mask &= ~mm;
    }
}

template <int NBIN>
__device__ void scan_one(const int* h, int rank, int* sc, int tid, int* outB, int* outR) {
    constexpr int PER = NBIN / 256;
    int s = 0;
#pragma unroll
    for (int j = 0; j < PER; j++) s += h[tid * PER + j];
    sc[tid] = s;
    __syncthreads();
    if (tid == 0) {
        int run = 0, cc = 0, rem = 0;
        for (int k = 0; k < 256; k++) {
            int v = sc[k];
            if (run + v > rank) { cc = k; rem = rank - run; break; }
            run += v;
        }
        int b = cc * PER;
        for (int j = 0; j < PER; j++) {
            int v = h[cc * PER + j];
            if (rem < v) { b = cc * PER + j; break; }
            rem -= v;
        }
        *outB = b; *outR = rem;
    }
    __syncthreads();
}

__global__ __launch_bounds__(THB) void post_kernel(const float* __restrict__ xf,
                                                   int* __restrict__ ctrl,
                                                   float* __restrict__ ws,
                                                   float* __restrict__ out)
{
    __shared__ int lh[8192];
    __shared__ int sc[256];
    __shared__ int binT[4], remT[4];
    __shared__ float frd[4][4];
    const int tid = threadIdx.x, bl = blockIdx.x;
    int* cnt = ctrl + GB_OFF;

    float xv[4]; unsigned kv[4];
#pragma unroll
    for (int k = 0; k < 4; k++) {
        xv[k] = xf[bl * THB + tid + k * CH];
        kv[k] = fkey(xv[k]);
    }

    // phase 0: zero global hists
    int g = bl * THB + tid;
    if (g < HTOT) ctrl[H1_OFF + g] = 0;
    gbar(cnt, 1 * NBLK);

    // ---- pass 1 hist (top 11 bits) ----
    for (int i = tid; i < 2048; i += THB) lh[i] = 0;
    __syncthreads();
#pragma unroll
    for (int k = 0; k < 4; k++) aggAdd(lh, (int)(kv[k] >> 21));
    __syncthreads();
    for (int i = tid; i < 2048; i += THB) { int v = lh[i]; if (v) atomicAdd(&ctrl[H1_OFF + i], v); }
    gbar(cnt, 2 * NBLK);

    // ---- scan 1 (block 0) ----
    if (bl == 0) {
        const int RANKS[4] = {13107, 13108, 249035, 249036};
        for (int t = 0; t < 4; t++)
            scan_one<2048>(ctrl + H1_OFF, RANKS[t], sc, tid, &binT[t], &remT[t]);
        if (tid == 0) {
            for (int t = 0; t < 4; t++) { ctrl[ST_OFF + t] = binT[t]; ctrl[ST_OFF + 4 + t] = remT[t]; }
            for (int t = 0; t < 4; t++) {
                int gq = t;
                for (int q = 0; q < t; q++) if (binT[q] == binT[t]) { gq = q; break; }
                ctrl[ST_OFF + 8 + t] = gq;
            }
        }
    }
    gbar(cnt, 3 * NBLK);

    // ---- pass 2 hist (next 11 bits, grouped by matched prefix) ----
    {
        int pf[4], gp[4];
#pragma unroll
        for (int t = 0; t < 4; t++) { pf[t] = ctrl[ST_OFF + t]; gp[t] = ctrl[ST_OFF + 8 + t]; }
        for (int i = tid; i < 8192; i += THB) lh[i] = 0;
        __syncthreads();
#pragma unroll
        for (int k = 0; k < 4; k++) {
            unsigned hi = kv[k] >> 21;
            int bin = (int)((kv[k] >> 10) & 2047u);
            int code = -1;
#pragma unroll
            for (int t = 0; t < 4; t++)
                if (gp[t] == t && (unsigned)pf[t] == hi) code = t * 2048 + bin;
            aggAdd(lh, code);
        }
        __syncthreads();
        for (int i = tid; i < 8192; i += THB) { int v = lh[i]; if (v) atomicAdd(&ctrl[H2_OFF + i], v); }
    }
    gbar(cnt, 4 * NBLK);

    // ---- scan 2 (block 0) ----
    if (bl == 0) {
        for (int t = 0; t < 4; t++) {
            int gq = ctrl[ST_OFF + 8 + t], rank = ctrl[ST_OFF + 4 + t];
            scan_one<2048>(ctrl + H2_OFF + gq * 2048, rank, sc, tid, &binT[t], &remT[t]);
        }
        if (tid == 0) {
            int P2n[4];
            for (int t = 0; t < 4; t++) {
                P2n[t] = (ctrl[ST_OFF + t] << 11) | binT[t];
                ctrl[ST_OFF + 12 + t] = P2n[t];
                ctrl[ST_OFF + 16 + t] = remT[t];
            }
            for (int t = 0; t < 4; t++) {
                int gq = t;
                for (int q = 0; q < t; q++) if (P2n[q] == P2n[t]) { gq = q; break; }
                ctrl[ST_OFF + 20 + t] = gq;
            }
        }
    }
    gbar(cnt, 5 * NBLK);

    // ---- pass 3 hist (low 10 bits) ----
    {
        int pf[4], gp[4];
#pragma unroll
        for (int t = 0; t < 4; t++) { pf[t] = ctrl[ST_OFF + 12 + t]; gp[t] = ctrl[ST_OFF + 20 + t]; }
        for (int i = tid; i < 4096; i += THB) lh[i] = 0;
        __syncthreads();
#pragma unroll
        for (int k = 0; k < 4; k++) {
            unsigned hi = kv[k] >> 10;
            int bin = (int)(kv[k] & 1023u);
            int code = -1;
#pragma unroll
            for (int t = 0; t < 4; t++)
                if (gp[t] == t && (unsigned)pf[t] == hi) code = t * 1024 + bin;
            aggAdd(lh, code);
        }
        __syncthreads();
        for (int i = tid; i < 4096; i += THB) { int v = lh[i]; if (v) atomicAdd(&ctrl[H3_OFF + i], v); }
    }
    gbar(cnt, 6 * NBLK);

    // ---- scan 3 (block 0) -> p5/p95 ----
    if (bl == 0) {
        for (int t = 0; t < 4; t++) {
            int gq = ctrl[ST_OFF + 20 + t], rank = ctrl[ST_OFF + 16 + t];
            scan_one<1024>(ctrl + H3_OFF + gq * 1024, rank, sc, tid, &binT[t], &remT[t]);
        }
        if (tid == 0) {
            float* sf = (float*)(ctrl + SF_OFF);
            float v[4];
            for (int t = 0; t < 4; t++) {
                unsigned key = ((unsigned)ctrl[ST_OFF + 12 + t] << 10) | (unsigned)binT[t];
                v[t] = funkey(key);
                sf[t] = v[t];
            }
            sf[4] = v[0] + 0.15f * (v[1] - v[0]);  // p5  (idx 0.05*(B-1)=13107.15)
            sf[5] = v[2] + 0.85f * (v[3] - v[2]);  // p95 (idx 0.95*(B-1)=249035.85)
        }
    }
    gbar(cnt, 7 * NBLK);

    // ---- tail CVaR partial sums (values still in registers) ----
    {
        const float* sf = (const float*)(ctrl + SF_OFF);
        const float p5 = sf[4], p95 = sf[5];
        float slo = 0.f, clo = 0.f, shi = 0.f, chi = 0.f;
#pragma unroll
        for (int k = 0; k < 4; k++) {
            float xx = xv[k];
            if (xx < p5)  { slo += xx; clo += 1.f; }
            if (xx > p95) { shi += xx; chi += 1.f; }
        }
        slo = wred(slo); clo = wred(clo); shi = wred(shi); chi = wred(chi);
        int wid = tid >> 6, lane = tid & 63;
        if (lane == 0) { frd[wid][0] = slo; frd[wid][1] = clo; frd[wid][2] = shi; frd[wid][3] = chi; }
        __syncthreads();
        if (tid == 0) {
            float s0 = 0, s1 = 0, s2 = 0, s3 = 0;
#pragma unroll
            for (int w = 0; w < 4; w++) { s0 += frd[w][0]; s1 += frd[w][1]; s2 += frd[w][2]; s3 += frd[w][3]; }
            float* tp = ws + TAILP_OFF + bl * 4;
            tp[0] = s0; tp[1] = s1; tp[2] = s2; tp[3] = s3;
        }
    }
    gbar(cnt, 8 * NBLK);

    // ---- final tail reduce (block 0) ----
    if (bl != 0) return;
    {
        const float* tp = ws + TAILP_OFF;
        float a0 = tp[tid * 4 + 0], a1 = tp[tid * 4 + 1], a2 = tp[tid * 4 + 2], a3 = tp[tid * 4 + 3];
        a0 = wred(a0); a1 = wred(a1); a2 = wred(a2); a3 = wred(a3);
        int wid = tid >> 6, lane = tid & 63;
        if (lane == 0) { frd[wid][0] = a0; frd[wid][1] = a1; frd[wid][2] = a2; frd[wid][3] = a3; }
        __syncthreads();
        if (tid == 0) {
            float Slo = 0, Clo = 0, Shi = 0, Chi = 0;
#pragma unroll
            for (int w = 0; w < 4; w++) { Slo += frd[w][0]; Clo += frd[w][1]; Shi += frd[w][2]; Chi += frd[w][3]; }
            out[2] = -Slo / fmaxf(Clo, 1.f);
            out[3] = -Shi / fmaxf(Chi, 1.f);
        }
    }
}

// ---------------- host ----------------
extern "C" void kernel_launch(void* const* d_in, const int* in_sizes, int n_in,
                              void* d_out, int out_size, void* d_ws, size_t ws_size,
                              hipStream_t stream)
{
    const float* x_in = (const float*)d_in[0];
    const float* dW   = (const float*)d_in[1];
    const float* Wo   = (const float*)d_in[2];
    const float* bo   = (const float*)d_in[3];
    const float* Wk   = (const float*)d_in[4];
    const float* bk   = (const float*)d_in[5];
    const float* Wu0  = (const float*)d_in[6];
    const float* bu0  = (const float*)d_in[7];
    const float* W1   = (const float*)d_in[8];
    const float* b1   = (const float*)d_in[9];
    const float* W2   = (const float*)d_in[10];
    const float* b2   = (const float*)d_in[11];
    const float* W3   = (const float*)d_in[12];
    const float* b3   = (const float*)d_in[13];
    float* ws  = (float*)d_ws;
    int* ctrl  = (int*)d_ws + ICTRL;
    float* out = (float*)d_out;

    zero_kernel<<<1, 64, 0, stream>>>(ctrl);
    sim_kernel<<<NBLK, THB, 0, stream>>>(x_in, dW, Wo, bo, Wk, bk, Wu0, bu0,
                                         W1, b1, W2, b2, W3, b3, ws, ctrl, out);
    post_kernel<<<NBLK, THB, 0, stream>>>(ws, ctrl, ws, out);
}

// Round 3
// 385.421 us; speedup vs baseline: 1.3943x; 1.3943x over previous
//
#include <hip/hip_runtime.h>
#include <math.h>

// ---------------- problem constants ----------------
#define BB 262144
#define NST 20
#define RHc 0.006f            // R*H
#define BHc 0.01f             // B_DRIFT*H
#define SIGc 0.2f
#define CURTc 0.005f
#define DISCf 0.8869204367171575f   // exp(-0.12)

// ---------------- launch geometry ----------------
#define THB_SIM 256
#define NBLK_SIM 1024          // 1 path/thread
#define THB_POST 1024
#define NBLK_POST 8            // one block per XCD -> 8 barrier pollers only
#define VPT 32                 // values per post thread (8 float4)

// ---------------- workspace layout (4-byte units) ----------------
#define SIMP_OFF  BB                         // float[NBLK_SIM*5]
#define TAILP_OFF (SIMP_OFF + NBLK_SIM * 5)  // float[NBLK_POST*4]
#define ICTRL     (TAILP_OFF + NBLK_POST * 4)
// ctrl (int) layout
#define H1_OFF 0                              // 2048
#define H2_OFF 2048                           // 4*2048
#define H3_OFF (H2_OFF + 4 * 2048)            // 4*1024
#define HTOT   (H3_OFF + 4 * 1024)            // 14336
#define CNT_OFF HTOT                          // sim last-block counter
#define GB_OFF  (HTOT + 1)                    // grid-barrier counter
#define ST_OFF  (HTOT + 8)                    // ints: P1[4] R1[4] G2[4] P2[4] R2[4] G3[4]
#define SF_OFF  (ST_OFF + 24)                 // floats: vals[4], p5, p95
#define ZERO_N  8

// ---------------- helpers ----------------
__device__ __forceinline__ unsigned fkey(float f) {
    unsigned u = __float_as_uint(f);
    return (u & 0x80000000u) ? ~u : (u | 0x80000000u);
}
__device__ __forceinline__ float funkey(unsigned k) {
    return __uint_as_float((k & 0x80000000u) ? (k ^ 0x80000000u) : ~k);
}
__device__ __forceinline__ float wred(float v) {
#pragma unroll
    for (int o = 32; o > 0; o >>= 1) v += __shfl_down(v, o);
    return v;
}
// device-scope grid barrier; only NBLK_POST(=8) pollers -> no fabric contention
__device__ __forceinline__ void gbar(int* cnt, int target) {
    __syncthreads();
    __threadfence();
    if (threadIdx.x == 0) {
        __hip_atomic_fetch_add(cnt, 1, __ATOMIC_ACQ_REL, __HIP_MEMORY_SCOPE_AGENT);
        while (__hip_atomic_load(cnt, __ATOMIC_ACQUIRE, __HIP_MEMORY_SCOPE_AGENT) < target)
            __builtin_amdgcn_s_sleep(16);
    }
    __syncthreads();
    __threadfence();
}

__global__ void zero_kernel(int* __restrict__ ctrl) {
    int i = threadIdx.x;
    if (i < ZERO_N) ctrl[CNT_OFF + i] = 0;
}

// ---------------- main simulation: 1 path/thread, weights via uniform (scalar) loads ----------------
__global__ __launch_bounds__(THB_SIM, 4) void sim_kernel(
    const float* __restrict__ x_in, const float* __restrict__ dW,
    const float* __restrict__ Wo, const float* __restrict__ bo,
    const float* __restrict__ Wk, const float* __restrict__ bk,
    const float* __restrict__ Wu0, const float* __restrict__ bu0,
    const float* __restrict__ W1, const float* __restrict__ b1,
    const float* __restrict__ W2, const float* __restrict__ b2,
    const float* __restrict__ W3, const float* __restrict__ b3,
    float* __restrict__ ws, int* __restrict__ ctrl, float* __restrict__ out)
{
    __shared__ float red[4][5];
    __shared__ int lastF;
    const int tid = threadIdx.x;
    const int b = blockIdx.x * THB_SIM + tid;

    float x = x_in[b];

    // softmax over 11 logits -> last component (mean = loss7)
    float z[11], zm = -1e30f;
#pragma unroll
    for (int j = 0; j < 11; j++) {
        z[j] = fmaf(x, Wo[j], bo[j]);
        zm = fmaxf(zm, z[j]);
    }
    float se = 0.f;
#pragma unroll
    for (int j = 0; j < 11; j++) se += __expf(z[j] - zm);
    float smv = __expf(z[10] - zm) / se;

    float K0 = 1.f + 0.25f * tanhf(fmaf(x, Wk[0], bk[0]));

    float alpha[5], S[5], SQ[5], dN[5], Nm1[5], dwb[5];
#pragma unroll
    for (int d = 0; d < 5; d++) {
        alpha[d] = fmaf(x, Wu0[d], bu0[d]);
        S[d] = 1.f; SQ[d] = 1.f; dN[d] = 0.f;
        Nm1[d] = alpha[d];
    }
    {
        const float* pw = dW + (size_t)b * 5;
#pragma unroll
        for (int d = 0; d < 5; d++) dwb[d] = pw[d];
    }

#pragma unroll 1
    for (int n = 1; n <= NST; n++) {
        float dwc[5];
#pragma unroll
        for (int d = 0; d < 5; d++) dwc[d] = dwb[d];
        if (n < NST) {
            const float* pw = dW + ((size_t)n * BB + b) * 5;
#pragma unroll
            for (int d = 0; d < 5; d++) dwb[d] = pw[d];
        }
        float usum = 0.f, du = 0.f;
#pragma unroll
        for (int d = 0; d < 5; d++) {
            float u = alpha[d];
            float Np = u * __builtin_amdgcn_rcpf(S[d]);
            dN[d] += fabsf(Np - Nm1[d]);
            Nm1[d] = Np;
            usum += u;
            du = fmaf(u, fmaf(SIGc, dwc[d], BHc), du);
        }
        x = fmaf(x - usum, RHc, x) + du;
#pragma unroll
        for (int d = 0; d < 5; d++) {
            float g = SIGc * dwc[d];
            S[d]  *= (1.f + BHc + g);
            SQ[d] *= (1.f + RHc + g);
        }
        if (n < NST) {
            // all weight addresses depend only on n (wave-uniform) -> scalar loads
            const float* Lw1 = W1 + (n - 1) * 20;
            const float* Lb1 = b1 + (n - 1) * 20;
            const float* Lw2 = W2 + (n - 1) * 400;
            const float* Lb2 = b2 + (n - 1) * 20;
            const float* Lw3 = W3 + (n - 1) * 100;
            const float* Lb3 = b3 + (n - 1) * 5;

            float h2[20];
#pragma unroll
            for (int j = 0; j < 20; j++) h2[j] = Lb2[j];
#pragma unroll
            for (int i = 0; i < 20; i++) {
                float hv = fmaxf(fmaf(x, Lw1[i], Lb1[i]), 0.f);
                const float* wr = Lw2 + i * 20;
#pragma unroll
                for (int j = 0; j < 20; j++) h2[j] = fmaf(hv, wr[j], h2[j]);
            }
#pragma unroll
            for (int j = 0; j < 20; j++) h2[j] = fmaxf(h2[j], 0.f);
#pragma unroll
            for (int k = 0; k < 5; k++) {
                float a = Lb3[k];
#pragma unroll
                for (int i = 0; i < 20; i++) a = fmaf(h2[i], Lw3[i * 5 + k], a);
                alpha[k] = a;
            }
        }
    }

    float dNs = dN[0] + dN[1] + dN[2] + dN[3] + dN[4];
    float xx = fmaf(-CURTc, dNs, x);
    ws[b] = xx;
    float v0 = xx, v1 = xx * xx;
    float v2 = fmaxf(S[0]  - K0, 0.f);
    float v3 = fmaxf(SQ[0] - K0, 0.f);
    float v4 = smv;

    v0 = wred(v0); v1 = wred(v1); v2 = wred(v2); v3 = wred(v3); v4 = wred(v4);
    int wid = tid >> 6, lane = tid & 63;
    if (lane == 0) { red[wid][0] = v0; red[wid][1] = v1; red[wid][2] = v2; red[wid][3] = v3; red[wid][4] = v4; }
    __syncthreads();
    if (tid == 0) {
        float s0 = 0, s1 = 0, s2 = 0, s3 = 0, s4 = 0;
#pragma unroll
        for (int w = 0; w < 4; w++) { s0 += red[w][0]; s1 += red[w][1]; s2 += red[w][2]; s3 += red[w][3]; s4 += red[w][4]; }
        float* part = ws + SIMP_OFF + blockIdx.x * 5;
        part[0] = s0; part[1] = s1; part[2] = s2; part[3] = s3; part[4] = s4;
    }
    __threadfence();
    if (tid == 0) lastF = (atomicAdd(&ctrl[CNT_OFF], 1) == NBLK_SIM - 1);
    __syncthreads();
    if (!lastF) return;
    __threadfence();

    // deterministic final reduce of 1024 partial rows with 256 threads
    const float* part = ws + SIMP_OFF;
    float a0 = 0, a1 = 0, a2 = 0, a3 = 0, a4 = 0;
    for (int r = tid; r < NBLK_SIM; r += THB_SIM) {
        const float* pr = part + r * 5;
        a0 += pr[0]; a1 += pr[1]; a2 += pr[2]; a3 += pr[3]; a4 += pr[4];
    }
    a0 = wred(a0); a1 = wred(a1); a2 = wred(a2); a3 = wred(a3); a4 = wred(a4);
    if (lane == 0) { red[wid][0] = a0; red[wid][1] = a1; red[wid][2] = a2; red[wid][3] = a3; red[wid][4] = a4; }
    __syncthreads();
    if (tid == 0) {
        float Sx = 0, Sx2 = 0, SP = 0, SQs = 0, Ssm = 0;
#pragma unroll
        for (int w = 0; w < 4; w++) { Sx += red[w][0]; Sx2 += red[w][1]; SP += red[w][2]; SQs += red[w][3]; Ssm += red[w][4]; }
        float invB = 1.f / (float)BB;
        float meanx = Sx * invB;
        out[0] = -meanx;
        out[1] = Sx2 * invB - meanx * meanx;
        out[4] = (SP * invB) / (DISCf * (SQs * invB) + 1e-8f);
        out[5] = 1.f + 0.25f * tanhf(fmaf(x_in[0], Wk[1], bk[1]));
        out[6] = Ssm * invB;
    }
}

// ---------------- fused select + tail kernel (8 blocks x 1024) ----------------
__device__ __forceinline__ void aggAdd(int* lh, int code) {
    bool act = (code >= 0);
    unsigned long long mask = __ballot(act);
    while (mask) {
        int leader = __ffsll((unsigned long long)mask) - 1;
        int lc = __shfl(code, leader);
        unsigned long long mm = __ballot(act && code == lc);
        if ((threadIdx.x & 63) == leader) atomicAdd(&lh[lc], (int)__popcll(mm));
        mask &= ~mm;
    }
}

// exclusive prefix over 1024 threads (16 waves)
__device__ int excl_scan1024(int v, int tid, int* wsum) {
    __syncthreads();                    // protect wsum reuse across calls
    int lane = tid & 63, wid = tid >> 6;
    int inc = v;
#pragma unroll
    for (int o = 1; o < 64; o <<= 1) { int u = __shfl_up(inc, o); if (lane >= o) inc += u; }
    if (lane == 63) wsum[wid] = inc;
    __syncthreads();
    if (tid < 16) {
        int wv = wsum[tid], winc = wv;
#pragma unroll
        for (int o = 1; o < 16; o <<= 1) { int u = __shfl_up(winc, o); if (tid >= o) winc += u; }
        wsum[tid] = winc - wv;          // exclusive wave offset
    }
    __syncthreads();
    return wsum[wid] + inc - v;
}

template <int PER>
__device__ void scan_find(const int* h, const int* ranks, int ntar, int tid,
                          int* wsum, int* outB, int* outR) {
    int c[PER]; int s = 0;
#pragma unroll
    for (int j = 0; j < PER; j++) { c[j] = h[tid * PER + j]; s += c[j]; }
    int E = excl_scan1024(s, tid, wsum);
    for (int t = 0; t < ntar; t++) {
        int r = ranks[t];
        if (r >= E && r < E + s) {
            int run = E;
#pragma unroll
            for (int j = 0; j < PER; j++) {
                if (r < run + c[j]) { outB[t] = tid * PER + j; outR[t] = r - run; break; }
                run += c[j];
            }
        }
    }
    __syncthreads();
}

__global__ __launch_bounds__(THB_POST) void post_kernel(const float* __restrict__ xf,
                                                        int* __restrict__ ctrl,
                                                        float* __restrict__ ws,
                                                        float* __restrict__ out)
{
    __shared__ int lh[8192];
    __shared__ int wsum[16];
    __shared__ int binT[4], remT[4];
    __shared__ float frd[16][4];
    const int tid = threadIdx.x, bl = blockIdx.x;
    int* cnt = ctrl + GB_OFF;

    // load this thread's 32 values into registers (vectorized)
    float xv[VPT];
    {
        const float4* xf4 = (const float4*)xf;
#pragma unroll
        for (int w = 0; w < 8; w++) {
            float4 v = xf4[(size_t)bl * 8192 + w * 1024 + tid];
            xv[w * 4 + 0] = v.x; xv[w * 4 + 1] = v.y;
            xv[w * 4 + 2] = v.z; xv[w * 4 + 3] = v.w;
        }
    }

    // phase 0: zero global hists
    for (int i = bl * THB_POST + tid; i < HTOT; i += NBLK_POST * THB_POST) ctrl[i] = 0;
    gbar(cnt, 1 * NBLK_POST);

    // ---- pass 1: top 11 bits ----
    for (int i = tid; i < 2048; i += THB_POST) lh[i] = 0;
    __syncthreads();
#pragma unroll
    for (int k = 0; k < VPT; k++) aggAdd(lh, (int)(fkey(xv[k]) >> 21));
    __syncthreads();
    for (int i = tid; i < 2048; i += THB_POST) { int v = lh[i]; if (v) atomicAdd(&ctrl[H1_OFF + i], v); }
    gbar(cnt, 2 * NBLK_POST);

    // ---- scan 1 (block 0) ----
    if (bl == 0) {
        const int RANKS[4] = {13107, 13108, 249035, 249036};
        scan_find<2>(ctrl + H1_OFF, RANKS, 4, tid, wsum, binT, remT);
        if (tid == 0) {
            for (int t = 0; t < 4; t++) { ctrl[ST_OFF + t] = binT[t]; ctrl[ST_OFF + 4 + t] = remT[t]; }
            for (int t = 0; t < 4; t++) {
                int g = t;
                for (int q = 0; q < t; q++) if (binT[q] == binT[t]) { g = q; break; }
                ctrl[ST_OFF + 8 + t] = g;
            }
        }
    }
    gbar(cnt, 3 * NBLK_POST);

    // ---- pass 2: next 11 bits within matched prefixes ----
    {
        int pf[4], gp[4];
#pragma unroll
        for (int t = 0; t < 4; t++) { pf[t] = ctrl[ST_OFF + t]; gp[t] = ctrl[ST_OFF + 8 + t]; }
        for (int i = tid; i < 8192; i += THB_POST) lh[i] = 0;
        __syncthreads();
#pragma unroll
        for (int k = 0; k < VPT; k++) {
            unsigned u = fkey(xv[k]);
            unsigned hi = u >> 21;
            int bin = (int)((u >> 10) & 2047u);
            int code = -1;
#pragma unroll
            for (int t = 0; t < 4; t++)
                if (gp[t] == t && (unsigned)pf[t] == hi) code = t * 2048 + bin;
            aggAdd(lh, code);
        }
        __syncthreads();
        for (int i = tid; i < 8192; i += THB_POST) { int v = lh[i]; if (v) atomicAdd(&ctrl[H2_OFF + i], v); }
    }
    gbar(cnt, 4 * NBLK_POST);

    // ---- scan 2 (block 0) ----
    if (bl == 0) {
        for (int t = 0; t < 4; t++) {
            int g = ctrl[ST_OFF + 8 + t], rank = ctrl[ST_OFF + 4 + t];
            int rk[1] = {rank};
            scan_find<2>(ctrl + H2_OFF + g * 2048, rk, 1, tid, wsum, &binT[t], &remT[t]);
        }
        if (tid == 0) {
            int P2n[4];
            for (int t = 0; t < 4; t++) {
                P2n[t] = (ctrl[ST_OFF + t] << 11) | binT[t];
                ctrl[ST_OFF + 12 + t] = P2n[t];
                ctrl[ST_OFF + 16 + t] = remT[t];
            }
            for (int t = 0; t < 4; t++) {
                int g = t;
                for (int q = 0; q < t; q++) if (P2n[q] == P2n[t]) { g = q; break; }
                ctrl[ST_OFF + 20 + t] = g;
            }
        }
    }
    gbar(cnt, 5 * NBLK_POST);

    // ---- pass 3: low 10 bits ----
    {
        int pf[4], gp[4];
#pragma unroll
        for (int t = 0; t < 4; t++) { pf[t] = ctrl[ST_OFF + 12 + t]; gp[t] = ctrl[ST_OFF + 20 + t]; }
        for (int i = tid; i < 4096; i += THB_POST) lh[i] = 0;
        __syncthreads();
#pragma unroll
        for (int k = 0; k < VPT; k++) {
            unsigned u = fkey(xv[k]);
            unsigned hi = u >> 10;
            int bin = (int)(u & 1023u);
            int code = -1;
#pragma unroll
            for (int t = 0; t < 4; t++)
                if (gp[t] == t && (unsigned)pf[t] == hi) code = t * 1024 + bin;
            aggAdd(lh, code);
        }
        __syncthreads();
        for (int i = tid; i < 4096; i += THB_POST) { int v = lh[i]; if (v) atomicAdd(&ctrl[H3_OFF + i], v); }
    }
    gbar(cnt, 6 * NBLK_POST);

    // ---- scan 3 (block 0) -> p5/p95 ----
    if (bl == 0) {
        for (int t = 0; t < 4; t++) {
            int g = ctrl[ST_OFF + 20 + t], rank = ctrl[ST_OFF + 16 + t];
            int rk[1] = {rank};
            scan_find<1>(ctrl + H3_OFF + g * 1024, rk, 1, tid, wsum, &binT[t], &remT[t]);
        }
        if (tid == 0) {
            float* sf = (float*)(ctrl + SF_OFF);
            float v[4];
            for (int t = 0; t < 4; t++) {
                unsigned key = ((unsigned)ctrl[ST_OFF + 12 + t] << 10) | (unsigned)binT[t];
                v[t] = funkey(key);
                sf[t] = v[t];
            }
            sf[4] = v[0] + 0.15f * (v[1] - v[0]);  // p5  (idx 0.05*(B-1)=13107.15)
            sf[5] = v[2] + 0.85f * (v[3] - v[2]);  // p95 (idx 0.95*(B-1)=249035.85)
        }
    }
    gbar(cnt, 7 * NBLK_POST);

    // ---- tail CVaR partial sums (values in registers) ----
    {
        const float* sf = (const float*)(ctrl + SF_OFF);
        const float p5 = sf[4], p95 = sf[5];
        float slo = 0.f, clo = 0.f, shi = 0.f, chi = 0.f;
#pragma unroll
        for (int k = 0; k < VPT; k++) {
            float x = xv[k];
            if (x < p5)  { slo += x; clo += 1.f; }
            if (x > p95) { shi += x; chi += 1.f; }
        }
        slo = wred(slo); clo = wred(clo); shi = wred(shi); chi = wred(chi);
        int wid = tid >> 6, lane = tid & 63;
        if (lane == 0) { frd[wid][0] = slo; frd[wid][1] = clo; frd[wid][2] = shi; frd[wid][3] = chi; }
        __syncthreads();
        if (tid == 0) {
            float s0 = 0, s1 = 0, s2 = 0, s3 = 0;
#pragma unroll
            for (int w = 0; w < 16; w++) { s0 += frd[w][0]; s1 += frd[w][1]; s2 += frd[w][2]; s3 += frd[w][3]; }
            float* tp = ws + TAILP_OFF + bl * 4;
            tp[0] = s0; tp[1] = s1; tp[2] = s2; tp[3] = s3;
        }
    }
    gbar(cnt, 8 * NBLK_POST);

    // ---- final tail reduce (block 0) ----
    if (bl != 0) return;
    if (tid == 0) {
        const float* tp = ws + TAILP_OFF;
        float Slo = 0, Clo = 0, Shi = 0, Chi = 0;
        for (int r = 0; r < NBLK_POST; r++) {
            Slo += tp[r * 4 + 0]; Clo += tp[r * 4 + 1];
            Shi += tp[r * 4 + 2]; Chi += tp[r * 4 + 3];
        }
        out[2] = -Slo / fmaxf(Clo, 1.f);
        out[3] = -Shi / fmaxf(Chi, 1.f);
    }
}

// ---------------- host ----------------
extern "C" void kernel_launch(void* const* d_in, const int* in_sizes, int n_in,
                              void* d_out, int out_size, void* d_ws, size_t ws_size,
                              hipStream_t stream)
{
    const float* x_in = (const float*)d_in[0];
    const float* dW   = (const float*)d_in[1];
    const float* Wo   = (const float*)d_in[2];
    const float* bo   = (const float*)d_in[3];
    const float* Wk   = (const float*)d_in[4];
    const float* bk   = (const float*)d_in[5];
    const float* Wu0  = (const float*)d_in[6];
    const float* bu0  = (const float*)d_in[7];
    const float* W1   = (const float*)d_in[8];
    const float* b1   = (const float*)d_in[9];
    const float* W2   = (const float*)d_in[10];
    const float* b2   = (const float*)d_in[11];
    const float* W3   = (const float*)d_in[12];
    const float* b3   = (const float*)d_in[13];
    float* ws  = (float*)d_ws;
    int* ctrl  = (int*)d_ws + ICTRL;
    float* out = (float*)d_out;

    zero_kernel<<<1, 64, 0, stream>>>(ctrl);
    sim_kernel<<<NBLK_SIM, THB_SIM, 0, stream>>>(x_in, dW, Wo, bo, Wk, bk, Wu0, bu0,
                                                 W1, b1, W2, b2, W3, b3, ws, ctrl, out);
    post_kernel<<<NBLK_POST, THB_POST, 0, stream>>>(ws, ctrl, ws, out);
}

// Round 4
// 192.062 us; speedup vs baseline: 2.7981x; 2.0068x over previous
//
#include <hip/hip_runtime.h>
#include <math.h>

// ---------------- problem constants ----------------
#define BB 262144
#define NST 20
#define RHc 0.006f            // R*H
#define BHc 0.01f             // B_DRIFT*H
#define SIGc 0.2f
#define CURTc 0.005f
#define DISCf 0.8869204367171575f   // exp(-0.12)

// ---------------- launch geometry ----------------
#define P 4                    // paths per thread in sim
#define THB 256
#define NBLK_SIM 256           // B / (THB*P)
#define CH 65536               // path chunk stride = BB / P

#define H1_BLK 32              // hist1 blocks (per-block rows, no atomics)
#define H1_THR 1024
#define W_BLK 256              // wide pass blocks
#define W_THR 256

// ---------------- workspace layout ----------------
// floats: [0,BB) x | SIMP 256*5 | TAILP 256*4
#define SIMP_OFF  BB
#define TAILP_OFF (SIMP_OFF + NBLK_SIM * 5)
#define ICTRL     (TAILP_OFF + W_BLK * 4)
// ctrl ints:
#define H2_OFF 0                      // 4*2048
#define H3_OFF 8192                   // 4*1024
#define CNT_OFF 12288                 // sim last-block counter
#define ST_OFF  12296                 // P1[4] R1[4] G2[4] P2[4] R2[4] G3[4]
#define SF_OFF  12320                 // floats: v[4], p5, p95
#define ZTOT    12289                 // ints zeroed per call (H2,H3,CNT)
#define H1R_OFF 12352                 // 32 rows x 2048 ints

// ---------------- helpers ----------------
__device__ __forceinline__ unsigned fkey(float f) {
    unsigned u = __float_as_uint(f);
    return (u & 0x80000000u) ? ~u : (u | 0x80000000u);
}
__device__ __forceinline__ float funkey(unsigned k) {
    return __uint_as_float((k & 0x80000000u) ? (k ^ 0x80000000u) : ~k);
}
__device__ __forceinline__ float wred(float v) {
#pragma unroll
    for (int o = 32; o > 0; o >>= 1) v += __shfl_down(v, o);
    return v;
}
__device__ __forceinline__ unsigned short f2bf(float f) {   // RNE
    unsigned u = __float_as_uint(f);
    unsigned r = u + 0x7fffu + ((u >> 16) & 1u);
    return (unsigned short)(r >> 16);
}

__global__ void zero_kernel(int* __restrict__ ctrl) {
    int i = blockIdx.x * blockDim.x + threadIdx.x;
    if (i < ZTOT) ctrl[i] = 0;
}

// ---------------- sim: P=4 paths/thread, weights in LDS (W2 as bf16) ----------------
#define STRD 416               // dwords per step in LDS
#define HB   (19 * STRD)       // head region base
// step layout (dwords): [0,20) W1 | [20,40) b1 | [40,60) b2 | [60,160) W3T(k*20+i)
//                       [160,165) b3 | [168,408) W2 bf16 rows: 20 rows x 12 dwords (24 bf16, 20 used)

__global__ __launch_bounds__(THB, 1) void sim_kernel(
    const float* __restrict__ x_in, const float* __restrict__ dW,
    const float* __restrict__ Wo, const float* __restrict__ bo,
    const float* __restrict__ Wk, const float* __restrict__ bk,
    const float* __restrict__ Wu0, const float* __restrict__ bu0,
    const float* __restrict__ W1, const float* __restrict__ b1,
    const float* __restrict__ W2, const float* __restrict__ b2,
    const float* __restrict__ W3, const float* __restrict__ b3,
    float* __restrict__ ws, int* __restrict__ ctrl, float* __restrict__ out)
{
    __shared__ float L[HB + 40];
    __shared__ float red[4][5];
    __shared__ int lastF;
    const int tid = threadIdx.x;

    for (int t = tid; t < 19 * 20; t += THB) {
        int s = t / 20, j = t % 20;
        L[s * STRD + j]      = W1[t];
        L[s * STRD + 20 + j] = b1[t];
        L[s * STRD + 40 + j] = b2[t];
    }
    for (int t = tid; t < 19 * 100; t += THB) {
        int s = t / 100, r = t % 100, i = r / 5, k = r % 5;
        L[s * STRD + 60 + k * 20 + i] = W3[t];
    }
    for (int t = tid; t < 19 * 5; t += THB) {
        int s = t / 5, k = t % 5;
        L[s * STRD + 160 + k] = b3[t];
    }
    {
        unsigned short* Ls16 = (unsigned short*)L;
        for (int t = tid; t < 19 * 400; t += THB) {
            int s = t / 400, r = t % 400, i = r / 20, j = r % 20;
            Ls16[(s * STRD + 168 + i * 12) * 2 + j] = f2bf(W2[t]);
        }
        for (int t = tid; t < 19 * 80; t += THB) {     // zero pad j=20..23
            int s = t / 80, r = t % 80, i = r / 4, q = r % 4;
            Ls16[(s * STRD + 168 + i * 12) * 2 + 20 + q] = 0;
        }
    }
    if (tid < 11) { L[HB + tid] = Wo[tid]; L[HB + 11 + tid] = bo[tid]; }
    if (tid == 0) { L[HB + 22] = Wk[0]; L[HB + 23] = bk[0]; }
    if (tid < 5)  { L[HB + 24 + tid] = Wu0[tid]; L[HB + 29 + tid] = bu0[tid]; }
    __syncthreads();

    const int b0 = blockIdx.x * THB + tid;

    float x[P], K0[P], SQ0[P], dNs[P], smv = 0.f;
    float alpha[P][5], S[P][5], Nm1[P][5], dwb[P][5];

#pragma unroll
    for (int p = 0; p < P; p++) {
        int b = b0 + p * CH;
        float xx = x_in[b];
        x[p] = xx;
        float z[11], zm = -1e30f;
#pragma unroll
        for (int j = 0; j < 11; j++) {
            z[j] = fmaf(xx, L[HB + j], L[HB + 11 + j]);
            zm = fmaxf(zm, z[j]);
        }
        float se = 0.f;
#pragma unroll
        for (int j = 0; j < 11; j++) se += __expf(z[j] - zm);
        smv += __expf(z[10] - zm) / se;
        K0[p] = 1.f + 0.25f * tanhf(fmaf(xx, L[HB + 22], L[HB + 23]));
        SQ0[p] = 1.f; dNs[p] = 0.f;
#pragma unroll
        for (int d = 0; d < 5; d++) {
            alpha[p][d] = fmaf(xx, L[HB + 24 + d], L[HB + 29 + d]);
            S[p][d] = 1.f;
            Nm1[p][d] = alpha[p][d];
        }
        const float* pw = dW + (size_t)b * 5;
#pragma unroll
        for (int d = 0; d < 5; d++) dwb[p][d] = pw[d];
    }

#pragma unroll 1
    for (int n = 1; n <= NST; n++) {
        float dwc[P][5];
#pragma unroll
        for (int p = 0; p < P; p++)
#pragma unroll
            for (int d = 0; d < 5; d++) dwc[p][d] = dwb[p][d];
        if (n < NST) {
#pragma unroll
            for (int p = 0; p < P; p++) {
                const float* pw = dW + ((size_t)n * BB + b0 + p * CH) * 5;
#pragma unroll
                for (int d = 0; d < 5; d++) dwb[p][d] = pw[d];
            }
        }
#pragma unroll
        for (int p = 0; p < P; p++) {
            float usum = 0.f, du = 0.f, dn = 0.f;
#pragma unroll
            for (int d = 0; d < 5; d++) {
                float u = alpha[p][d];
                float Np = u * __builtin_amdgcn_rcpf(S[p][d]);
                dn += fabsf(Np - Nm1[p][d]);
                Nm1[p][d] = Np;
                usum += u;
                du = fmaf(u, fmaf(SIGc, dwc[p][d], BHc), du);
            }
            dNs[p] += dn;
            x[p] = fmaf(x[p] - usum, RHc, x[p]) + du;
#pragma unroll
            for (int d = 0; d < 5; d++)
                S[p][d] *= (1.f + BHc + SIGc * dwc[p][d]);
            SQ0[p] *= (1.f + RHc + SIGc * dwc[p][0]);
        }
        if (n < NST) {
            const float* Ls = L + (n - 1) * STRD;
            float h2[P][20];
#pragma unroll
            for (int j4 = 0; j4 < 5; j4++) {
                float4 c = *(const float4*)(Ls + 40 + j4 * 4);
#pragma unroll
                for (int p = 0; p < P; p++) {
                    h2[p][j4 * 4 + 0] = c.x; h2[p][j4 * 4 + 1] = c.y;
                    h2[p][j4 * 4 + 2] = c.z; h2[p][j4 * 4 + 3] = c.w;
                }
            }
#pragma unroll 1
            for (int i4 = 0; i4 < 5; i4++) {
                float4 w1c = *(const float4*)(Ls + i4 * 4);
                float4 c1c = *(const float4*)(Ls + 20 + i4 * 4);
#pragma unroll
                for (int ii = 0; ii < 4; ii++) {
                    int i = i4 * 4 + ii;
                    const uint4 q0 = *(const uint4*)(Ls + 168 + i * 12);
                    const uint4 q1 = *(const uint4*)(Ls + 168 + i * 12 + 4);
                    const uint2 q2 = *(const uint2*)(Ls + 168 + i * 12 + 8);
                    float w[20];
                    w[0]  = __uint_as_float(q0.x << 16); w[1]  = __uint_as_float(q0.x & 0xffff0000u);
                    w[2]  = __uint_as_float(q0.y << 16); w[3]  = __uint_as_float(q0.y & 0xffff0000u);
                    w[4]  = __uint_as_float(q0.z << 16); w[5]  = __uint_as_float(q0.z & 0xffff0000u);
                    w[6]  = __uint_as_float(q0.w << 16); w[7]  = __uint_as_float(q0.w & 0xffff0000u);
                    w[8]  = __uint_as_float(q1.x << 16); w[9]  = __uint_as_float(q1.x & 0xffff0000u);
                    w[10] = __uint_as_float(q1.y << 16); w[11] = __uint_as_float(q1.y & 0xffff0000u);
                    w[12] = __uint_as_float(q1.z << 16); w[13] = __uint_as_float(q1.z & 0xffff0000u);
                    w[14] = __uint_as_float(q1.w << 16); w[15] = __uint_as_float(q1.w & 0xffff0000u);
                    w[16] = __uint_as_float(q2.x << 16); w[17] = __uint_as_float(q2.x & 0xffff0000u);
                    w[18] = __uint_as_float(q2.y << 16); w[19] = __uint_as_float(q2.y & 0xffff0000u);
                    float wv = (ii == 0) ? w1c.x : (ii == 1) ? w1c.y : (ii == 2) ? w1c.z : w1c.w;
                    float cv = (ii == 0) ? c1c.x : (ii == 1) ? c1c.y : (ii == 2) ? c1c.z : c1c.w;
#pragma unroll
                    for (int p = 0; p < P; p++) {
                        float hv = fmaxf(fmaf(x[p], wv, cv), 0.f);
#pragma unroll
                        for (int j = 0; j < 20; j++)
                            h2[p][j] = fmaf(hv, w[j], h2[p][j]);
                    }
                }
            }
#pragma unroll
            for (int p = 0; p < P; p++)
#pragma unroll
                for (int j = 0; j < 20; j++) h2[p][j] = fmaxf(h2[p][j], 0.f);
#pragma unroll
            for (int k = 0; k < 5; k++) {
                const float* wr = Ls + 60 + k * 20;
                float4 wa  = *(const float4*)(wr + 0);
                float4 wb2 = *(const float4*)(wr + 4);
                float4 wc2 = *(const float4*)(wr + 8);
                float4 wd2 = *(const float4*)(wr + 12);
                float4 we2 = *(const float4*)(wr + 16);
                float bb = Ls[160 + k];
#pragma unroll
                for (int p = 0; p < P; p++) {
                    float a = bb;
                    a = fmaf(h2[p][0], wa.x, a);  a = fmaf(h2[p][1], wa.y, a);
                    a = fmaf(h2[p][2], wa.z, a);  a = fmaf(h2[p][3], wa.w, a);
                    a = fmaf(h2[p][4], wb2.x, a); a = fmaf(h2[p][5], wb2.y, a);
                    a = fmaf(h2[p][6], wb2.z, a); a = fmaf(h2[p][7], wb2.w, a);
                    a = fmaf(h2[p][8], wc2.x, a); a = fmaf(h2[p][9], wc2.y, a);
                    a = fmaf(h2[p][10], wc2.z, a); a = fmaf(h2[p][11], wc2.w, a);
                    a = fmaf(h2[p][12], wd2.x, a); a = fmaf(h2[p][13], wd2.y, a);
                    a = fmaf(h2[p][14], wd2.z, a); a = fmaf(h2[p][15], wd2.w, a);
                    a = fmaf(h2[p][16], we2.x, a); a = fmaf(h2[p][17], we2.y, a);
                    a = fmaf(h2[p][18], we2.z, a); a = fmaf(h2[p][19], we2.w, a);
                    alpha[p][k] = a;
                }
            }
        }
    }

    float v0 = 0.f, v1 = 0.f, v2 = 0.f, v3 = 0.f, v4 = smv;
#pragma unroll
    for (int p = 0; p < P; p++) {
        float xx = fmaf(-CURTc, dNs[p], x[p]);
        ws[b0 + p * CH] = xx;
        v0 += xx; v1 += xx * xx;
        v2 += fmaxf(S[p][0] - K0[p], 0.f);
        v3 += fmaxf(SQ0[p]  - K0[p], 0.f);
    }

    v0 = wred(v0); v1 = wred(v1); v2 = wred(v2); v3 = wred(v3); v4 = wred(v4);
    int wid = tid >> 6, lane = tid & 63;
    if (lane == 0) { red[wid][0] = v0; red[wid][1] = v1; red[wid][2] = v2; red[wid][3] = v3; red[wid][4] = v4; }
    __syncthreads();
    if (tid == 0) {
        float s0 = 0, s1 = 0, s2 = 0, s3 = 0, s4 = 0;
#pragma unroll
        for (int w = 0; w < 4; w++) { s0 += red[w][0]; s1 += red[w][1]; s2 += red[w][2]; s3 += red[w][3]; s4 += red[w][4]; }
        float* part = ws + SIMP_OFF + blockIdx.x * 5;
        part[0] = s0; part[1] = s1; part[2] = s2; part[3] = s3; part[4] = s4;
    }
    __threadfence();
    if (tid == 0) lastF = (atomicAdd(&ctrl[CNT_OFF], 1) == NBLK_SIM - 1);
    __syncthreads();
    if (!lastF) return;
    __threadfence();

    const float* part = ws + SIMP_OFF;
    float a0 = part[tid * 5 + 0], a1 = part[tid * 5 + 1], a2 = part[tid * 5 + 2],
          a3 = part[tid * 5 + 3], a4 = part[tid * 5 + 4];
    a0 = wred(a0); a1 = wred(a1); a2 = wred(a2); a3 = wred(a3); a4 = wred(a4);
    if (lane == 0) { red[wid][0] = a0; red[wid][1] = a1; red[wid][2] = a2; red[wid][3] = a3; red[wid][4] = a4; }
    __syncthreads();
    if (tid == 0) {
        float Sx = 0, Sx2 = 0, SP = 0, SQs = 0, Ssm = 0;
#pragma unroll
        for (int w = 0; w < 4; w++) { Sx += red[w][0]; Sx2 += red[w][1]; SP += red[w][2]; SQs += red[w][3]; Ssm += red[w][4]; }
        float invB = 1.f / (float)BB;
        float meanx = Sx * invB;
        out[0] = -meanx;
        out[1] = Sx2 * invB - meanx * meanx;
        out[4] = (SP * invB) / (DISCf * (SQs * invB) + 1e-8f);
        out[5] = 1.f + 0.25f * tanhf(fmaf(x_in[0], Wk[1], bk[1]));
        out[6] = Ssm * invB;
    }
}

// ---------------- select helpers ----------------
__device__ __forceinline__ void aggAdd(int* h, int code) {
    bool act = (code >= 0);
    unsigned long long mask = __ballot(act);
    while (mask) {
        int leader = __ffsll((unsigned long long)mask) - 1;
        int lc = __shfl(code, leader);
        unsigned long long mm = __ballot(act && code == lc);
        if ((threadIdx.x & 63) == leader) atomicAdd(&h[lc], (int)__popcll(mm));
        mask &= ~mm;
    }
}

// exclusive prefix over 1024 threads (16 waves)
__device__ int excl_scan1024(int v, int tid, int* wsum) {
    __syncthreads();
    int lane = tid & 63, wid = tid >> 6;
    int inc = v;
#pragma unroll
    for (int o = 1; o < 64; o <<= 1) { int u = __shfl_up(inc, o); if (lane >= o) inc += u; }
    if (lane == 63) wsum[wid] = inc;
    __syncthreads();
    if (tid < 16) {
        int wv = wsum[tid], winc = wv;
#pragma unroll
        for (int o = 1; o < 16; o <<= 1) { int u = __shfl_up(winc, o); if (tid >= o) winc += u; }
        wsum[tid] = winc - wv;
    }
    __syncthreads();
    return wsum[wid] + inc - v;
}

// ---------------- hist1: per-block LDS hist -> global rows ----------------
__global__ __launch_bounds__(H1_THR) void hist1_kernel(const float* __restrict__ xf,
                                                       int* __restrict__ ctrl)
{
    __shared__ int lh[2048];
    const int tid = threadIdx.x, bl = blockIdx.x;
    for (int i = tid; i < 2048; i += H1_THR) lh[i] = 0;
    __syncthreads();
    const float4* xf4 = (const float4*)xf;
#pragma unroll
    for (int w = 0; w < 2; w++) {
        float4 v = xf4[(size_t)bl * 2048 + w * 1024 + tid];
        aggAdd(lh, (int)(fkey(v.x) >> 21));
        aggAdd(lh, (int)(fkey(v.y) >> 21));
        aggAdd(lh, (int)(fkey(v.z) >> 21));
        aggAdd(lh, (int)(fkey(v.w) >> 21));
    }
    __syncthreads();
    int* row = ctrl + H1R_OFF + bl * 2048;
    for (int i = tid; i < 2048; i += H1_THR) row[i] = lh[i];
}

// ---------------- scan1 ----------------
__global__ __launch_bounds__(1024) void scan1_kernel(int* __restrict__ ctrl)
{
    __shared__ int wsum[16];
    __shared__ int binT[4], remT[4];
    const int tid = threadIdx.x;
    const int* rows = ctrl + H1R_OFF;
    int c0 = 0, c1 = 0;
    for (int r = 0; r < H1_BLK; r++) {
        c0 += rows[r * 2048 + 2 * tid];
        c1 += rows[r * 2048 + 2 * tid + 1];
    }
    int s = c0 + c1;
    int E = excl_scan1024(s, tid, wsum);
    const int RK[4] = {13107, 13108, 249035, 249036};
#pragma unroll
    for (int t = 0; t < 4; t++) {
        int r = RK[t];
        if (r >= E && r < E + s) {
            if (r < E + c0) { binT[t] = 2 * tid;     remT[t] = r - E; }
            else            { binT[t] = 2 * tid + 1; remT[t] = r - E - c0; }
        }
    }
    __syncthreads();
    if (tid == 0) {
        for (int t = 0; t < 4; t++) { ctrl[ST_OFF + t] = binT[t]; ctrl[ST_OFF + 4 + t] = remT[t]; }
        for (int t = 0; t < 4; t++) {
            int g = t;
            for (int q = 0; q < t; q++) if (binT[q] == binT[t]) { g = q; break; }
            ctrl[ST_OFF + 8 + t] = g;
        }
    }
}

// ---------------- hist2: matched-prefix values -> global atomics ----------------
__global__ __launch_bounds__(W_THR) void hist2_kernel(const float* __restrict__ xf,
                                                      int* __restrict__ ctrl)
{
    const int tid = threadIdx.x, bl = blockIdx.x;
    int pf[4], gp[4];
#pragma unroll
    for (int t = 0; t < 4; t++) { pf[t] = ctrl[ST_OFF + t]; gp[t] = ctrl[ST_OFF + 8 + t]; }
    float4 v = ((const float4*)xf)[(size_t)bl * W_THR + tid];
    float xv[4] = {v.x, v.y, v.z, v.w};
#pragma unroll
    for (int k = 0; k < 4; k++) {
        unsigned u = fkey(xv[k]);
        unsigned hi = u >> 21;
        int bin = (int)((u >> 10) & 2047u);
        int code = -1;
#pragma unroll
        for (int t = 0; t < 4; t++)
            if (gp[t] == t && (unsigned)pf[t] == hi) code = t * 2048 + bin;
        aggAdd(ctrl + H2_OFF, code);
    }
}

// ---------------- scan2 ----------------
__global__ __launch_bounds__(1024) void scan2_kernel(int* __restrict__ ctrl)
{
    __shared__ int wsum[16];
    __shared__ int binT[4], remT[4];
    const int tid = threadIdx.x;
    for (int t = 0; t < 4; t++) {
        int g = ctrl[ST_OFF + 8 + t], rank = ctrl[ST_OFF + 4 + t];
        const int* h = ctrl + H2_OFF + g * 2048;
        int c0 = h[2 * tid], c1 = h[2 * tid + 1];
        int s = c0 + c1;
        int E = excl_scan1024(s, tid, wsum);
        if (rank >= E && rank < E + s) {
            if (rank < E + c0) { binT[t] = 2 * tid;     remT[t] = rank - E; }
            else               { binT[t] = 2 * tid + 1; remT[t] = rank - E - c0; }
        }
        __syncthreads();
    }
    if (tid == 0) {
        int P2n[4];
        for (int t = 0; t < 4; t++) {
            P2n[t] = (ctrl[ST_OFF + t] << 11) | binT[t];
            ctrl[ST_OFF + 12 + t] = P2n[t];
            ctrl[ST_OFF + 16 + t] = remT[t];
        }
        for (int t = 0; t < 4; t++) {
            int g = t;
            for (int q = 0; q < t; q++) if (P2n[q] == P2n[t]) { g = q; break; }
            ctrl[ST_OFF + 20 + t] = g;
        }
    }
}

// ---------------- hist3 ----------------
__global__ __launch_bounds__(W_THR) void hist3_kernel(const float* __restrict__ xf,
                                                      int* __restrict__ ctrl)
{
    const int tid = threadIdx.x, bl = blockIdx.x;
    int pf[4], gp[4];
#pragma unroll
    for (int t = 0; t < 4; t++) { pf[t] = ctrl[ST_OFF + 12 + t]; gp[t] = ctrl[ST_OFF + 20 + t]; }
    float4 v = ((const float4*)xf)[(size_t)bl * W_THR + tid];
    float xv[4] = {v.x, v.y, v.z, v.w};
#pragma unroll
    for (int k = 0; k < 4; k++) {
        unsigned u = fkey(xv[k]);
        unsigned hi = u >> 10;
        int bin = (int)(u & 1023u);
        int code = -1;
#pragma unroll
        for (int t = 0; t < 4; t++)
            if (gp[t] == t && (unsigned)pf[t] == hi) code = t * 1024 + bin;
        aggAdd(ctrl + H3_OFF, code);
    }
}

// ---------------- scan3 -> p5/p95 ----------------
__global__ __launch_bounds__(1024) void scan3_kernel(int* __restrict__ ctrl)
{
    __shared__ int wsum[16];
    __shared__ int binT[4];
    const int tid = threadIdx.x;
    for (int t = 0; t < 4; t++) {
        int g = ctrl[ST_OFF + 20 + t], rank = ctrl[ST_OFF + 16 + t];
        const int* h = ctrl + H3_OFF + g * 1024;
        int s = h[tid];
        int E = excl_scan1024(s, tid, wsum);
        if (rank >= E && rank < E + s) binT[t] = tid;
        __syncthreads();
    }
    if (tid == 0) {
        float* sf = (float*)(ctrl + SF_OFF);
        float v[4];
        for (int t = 0; t < 4; t++) {
            unsigned key = ((unsigned)ctrl[ST_OFF + 12 + t] << 10) | (unsigned)binT[t];
            v[t] = funkey(key);
            sf[t] = v[t];
        }
        sf[4] = v[0] + 0.15f * (v[1] - v[0]);  // p5  (idx 0.05*(B-1)=13107.15)
        sf[5] = v[2] + 0.85f * (v[3] - v[2]);  // p95 (idx 0.95*(B-1)=249035.85)
    }
}

// ---------------- tail partials ----------------
__global__ __launch_bounds__(W_THR) void tail_kernel(const float* __restrict__ xf,
                                                     const int* __restrict__ ctrl,
                                                     float* __restrict__ ws)
{
    __shared__ float frd[4][4];
    const int tid = threadIdx.x, bl = blockIdx.x;
    const float* sf = (const float*)(ctrl + SF_OFF);
    const float p5 = sf[4], p95 = sf[5];
    float4 v = ((const float4*)xf)[(size_t)bl * W_THR + tid];
    float xv[4] = {v.x, v.y, v.z, v.w};
    float slo = 0.f, clo = 0.f, shi = 0.f, chi = 0.f;
#pragma unroll
    for (int k = 0; k < 4; k++) {
        float x = xv[k];
        if (x < p5)  { slo += x; clo += 1.f; }
        if (x > p95) { shi += x; chi += 1.f; }
    }
    slo = wred(slo); clo = wred(clo); shi = wred(shi); chi = wred(chi);
    int wid = tid >> 6, lane = tid & 63;
    if (lane == 0) { frd[wid][0] = slo; frd[wid][1] = clo; frd[wid][2] = shi; frd[wid][3] = chi; }
    __syncthreads();
    if (tid == 0) {
        float s0 = 0, s1 = 0, s2 = 0, s3 = 0;
#pragma unroll
        for (int w = 0; w < 4; w++) { s0 += frd[w][0]; s1 += frd[w][1]; s2 += frd[w][2]; s3 += frd[w][3]; }
        float* tp = ws + TAILP_OFF + bl * 4;
        tp[0] = s0; tp[1] = s1; tp[2] = s2; tp[3] = s3;
    }
}

// ---------------- tail final ----------------
__global__ __launch_bounds__(256) void tailfin_kernel(const float* __restrict__ ws,
                                                      float* __restrict__ out)
{
    __shared__ float frd[4][4];
    const int tid = threadIdx.x;
    const float* tp = ws + TAILP_OFF;
    float a0 = tp[tid * 4 + 0], a1 = tp[tid * 4 + 1], a2 = tp[tid * 4 + 2], a3 = tp[tid * 4 + 3];
    a0 = wred(a0); a1 = wred(a1); a2 = wred(a2); a3 = wred(a3);
    int wid = tid >> 6, lane = tid & 63;
    if (lane == 0) { frd[wid][0] = a0; frd[wid][1] = a1; frd[wid][2] = a2; frd[wid][3] = a3; }
    __syncthreads();
    if (tid == 0) {
        float Slo = 0, Clo = 0, Shi = 0, Chi = 0;
#pragma unroll
        for (int w = 0; w < 4; w++) { Slo += frd[w][0]; Clo += frd[w][1]; Shi += frd[w][2]; Chi += frd[w][3]; }
        out[2] = -Slo / fmaxf(Clo, 1.f);
        out[3] = -Shi / fmaxf(Chi, 1.f);
    }
}

// ---------------- host ----------------
extern "C" void kernel_launch(void* const* d_in, const int* in_sizes, int n_in,
                              void* d_out, int out_size, void* d_ws, size_t ws_size,
                              hipStream_t stream)
{
    const float* x_in = (const float*)d_in[0];
    const float* dW   = (const float*)d_in[1];
    const float* Wo   = (const float*)d_in[2];
    const float* bo   = (const float*)d_in[3];
    const float* Wk   = (const float*)d_in[4];
    const float* bk   = (const float*)d_in[5];
    const float* Wu0  = (const float*)d_in[6];
    const float* bu0  = (const float*)d_in[7];
    const float* W1   = (const float*)d_in[8];
    const float* b1   = (const float*)d_in[9];
    const float* W2   = (const float*)d_in[10];
    const float* b2   = (const float*)d_in[11];
    const float* W3   = (const float*)d_in[12];
    const float* b3   = (const float*)d_in[13];
    float* ws  = (float*)d_ws;
    int* ctrl  = (int*)d_ws + ICTRL;
    float* out = (float*)d_out;

    zero_kernel<<<(ZTOT + 1023) / 1024, 1024, 0, stream>>>(ctrl);
    sim_kernel<<<NBLK_SIM, THB, 0, stream>>>(x_in, dW, Wo, bo, Wk, bk, Wu0, bu0,
                                             W1, b1, W2, b2, W3, b3, ws, ctrl, out);
    hist1_kernel<<<H1_BLK, H1_THR, 0, stream>>>(ws, ctrl);
    scan1_kernel<<<1, 1024, 0, stream>>>(ctrl);
    hist2_kernel<<<W_BLK, W_THR, 0, stream>>>(ws, ctrl);
    scan2_kernel<<<1, 1024, 0, stream>>>(ctrl);
    hist3_kernel<<<W_BLK, W_THR, 0, stream>>>(ws, ctrl);
    scan3_kernel<<<1, 1024, 0, stream>>>(ctrl);
    tail_kernel<<<W_BLK, W_THR, 0, stream>>>(ws, ctrl, ws);
    tailfin_kernel<<<1, 256, 0, stream>>>(ws, out);
}